// Round 5
// baseline (976.413 us; speedup 1.0000x reference)
//
#include <hip/hip_runtime.h>

#define HID 50
#define LAT 16
#define MPW 16         // batch elements per wave (one MFMA M-tile)
#define ZSTR 36        // zbuf row stride (shorts). 36 % 16 == 4 -> 8q+col/2 bank spread (2-way, free)
#define HSTR 68        // hbuf row stride (shorts). 68 % 16 == 4 -> same property
// (stride % 16 == 4 puts quad back into the bank index; stride 32/64 made quad
//  vanish -> 8-way conflicts on every ds_write_b16 = the 1.34e8 conflict counter in R4)

typedef __attribute__((ext_vector_type(8))) short short8;  // 8 bf16 = 4 VGPRs
typedef __attribute__((ext_vector_type(4))) float f32x4;

#define MFMA16(a, b, c) __builtin_amdgcn_mfma_f32_16x16x32_bf16(a, b, c, 0, 0, 0)

// fp32 -> bf16 round-half-up
__device__ __forceinline__ short f2bf(float f) {
    unsigned u = __builtin_bit_cast(unsigned, f);
    return (short)((u + 0x8000u) >> 16);
}

__device__ __forceinline__ float fast_tanh(float x) {
    // tanh(x) = 1 - 2/(exp(2x)+1); exact +/-1 saturation, tanh(0)=0 exact
    float e = __expf(2.0f * x);
    return 1.0f - 2.0f * __builtin_amdgcn_rcpf(e + 1.0f);
}

// B-frag for stage-1 GEMM: W[Kreal x 50] row-major, K padded 16->32.
// k==16 is the bias slot (A supplies 1.0 there); col n==50 carries satval at k==16
// so that act(h[.,50]) == 1.0 feeds the stage-2 bias row.
__device__ __forceinline__ short8 bfragK16(const float* __restrict__ W, const float* __restrict__ bias,
                                           int Kreal, int n, int quad, float satval) {
    short8 v;
#pragma unroll
    for (int j = 0; j < 8; j++) {
        int k = quad * 8 + j;
        float f = 0.0f;
        if (n < HID) {
            if (k < Kreal)      f = W[k * HID + n];
            else if (k == LAT)  f = bias[n];
        } else if (n == HID) {
            if (k == LAT)       f = satval;
        }
        v[j] = f2bf(f);
    }
    return v;
}

// B-frag for stage-2 GEMM: W[50 x 16] row-major, K padded 50->64 in 2 chunks of 32.
// k==50 is the bias row (A supplies 1.0 there via the satval column).
__device__ __forceinline__ short8 bfragK64(const float* __restrict__ W, const float* __restrict__ bias,
                                           int n, int quad, int chunk) {
    short8 v;
#pragma unroll
    for (int j = 0; j < 8; j++) {
        int k = chunk * 32 + quad * 8 + j;
        float f = 0.0f;
        if (k < HID)       f = W[k * LAT + n];
        else if (k == HID) f = bias[n];
        v[j] = f2bf(f);
    }
    return v;
}

// Decoder stage-2 B-frag: output dim 1 (col 0 only), Wd2[50], bias bd2 at k==50.
__device__ __forceinline__ short8 bfragDec2(const float* __restrict__ Wd2, float bd2s,
                                            int n, int quad, int chunk) {
    short8 v;
#pragma unroll
    for (int j = 0; j < 8; j++) {
        int k = chunk * 32 + quad * 8 + j;
        float f = 0.0f;
        if (n == 0) {
            if (k < HID)       f = Wd2[k];
            else if (k == HID) f = bd2s;
        }
        v[j] = f2bf(f);
    }
    return v;
}

__global__ void __launch_bounds__(64, 4)
node_kernel(const float* __restrict__ x0, const float* __restrict__ tt,
            const float* __restrict__ We1, const float* __restrict__ be1,
            const float* __restrict__ We2, const float* __restrict__ be2,
            const float* __restrict__ Wo1, const float* __restrict__ bo1,
            const float* __restrict__ Wo2, const float* __restrict__ bo2,
            const float* __restrict__ Wd1, const float* __restrict__ bd1,
            const float* __restrict__ Wd2, const float* __restrict__ bd2,
            float* __restrict__ out, int B, int T) {
    // one wave per block, private LDS: zbuf [16 m][36 k] + hbuf [16 m][68 k] (bf16)
    __shared__ short lds_s[16 * ZSTR + 16 * HSTR];

    const int lane = threadIdx.x & 63;
    const int quad = lane >> 4;
    const int col  = lane & 15;
    const int wbase = blockIdx.x * MPW;

    short* zbuf = lds_s;
    short* hbuf = lds_s + 16 * ZSTR;

    // init zbuf: zero all rows (k=0..35), then k==16 bias slot = bf16(1.0).
    // k=17..31 stay zero forever (z writes touch only k=0..15).
    {
        int* zd = (int*)zbuf;
#pragma unroll
        for (int i = 0; i < 5; i++) {
            int idx = lane + 64 * i;
            if (idx < 16 * ZSTR / 2) zd[idx] = 0;
        }
        if (lane < MPW) zbuf[lane * ZSTR + LAT] = (short)0x3F80;
    }

    // precomputed LDS pointers (loop-invariant)
    short*       zw = zbuf + (quad * 4) * ZSTR + col;   // z' writes at zw[r*ZSTR]
    const short* zr = zbuf + col * ZSTR + quad * 8;     // A-frag read (b128)
    short*       hw = hbuf + (quad * 4) * HSTR + col;   // act writes at hw[r*HSTR + 16*ti]
    const short* hr = hbuf + col * HSTR + quad * 8;     // A-frag reads: hr[0], hr[32]

    // ---- persistent B-fragments (VGPRs for the whole kernel) ----
    short8 BWo1[4], BWd1[4];
    short8 BWo2[2], BWd2[2];
#pragma unroll
    for (int ti = 0; ti < 4; ti++) {
        BWo1[ti] = bfragK16(Wo1, bo1, LAT, col + 16 * ti, quad, 20.0f); // tanh(20)==1.0
        BWd1[ti] = bfragK16(Wd1, bd1, LAT, col + 16 * ti, quad, 1.0f);  // relu(1)==1.0
    }
#pragma unroll
    for (int c = 0; c < 2; c++) {
        BWo2[c] = bfragK64(Wo2, bo2, col, quad, c);
        BWd2[c] = bfragDec2(Wd2, bd2[0], col, quad, c);
    }
    const f32x4 zero4 = {0.0f, 0.0f, 0.0f, 0.0f};

    // ---- Encoder via MFMA (one-time; We-frags are transient) ----
    f32x4 z;
    {
        if (lane < MPW) {
            float xa = x0[2 * (wbase + lane)];
            float xb = x0[2 * (wbase + lane) + 1];
            unsigned pk = (unsigned)(unsigned short)f2bf(xa) |
                          ((unsigned)(unsigned short)f2bf(xb) << 16);
            *(unsigned*)(zbuf + lane * ZSTR) = pk;  // cols 0,1; cols 2..15 zero
        }
        short8 BWe1[4], BWe2[2];
#pragma unroll
        for (int ti = 0; ti < 4; ti++) BWe1[ti] = bfragK16(We1, be1, 2, col + 16 * ti, quad, 1.0f);
#pragma unroll
        for (int c = 0; c < 2; c++)    BWe2[c]  = bfragK64(We2, be2, col, quad, c);

        short8 az = *(const short8*)zr;
        f32x4 h[4];
#pragma unroll
        for (int ti = 0; ti < 4; ti++) h[ti] = MFMA16(az, BWe1[ti], zero4);
#pragma unroll
        for (int ti = 0; ti < 4; ti++)
#pragma unroll
            for (int r = 0; r < 4; r++)
                hw[r * HSTR + 16 * ti] = f2bf(fmaxf(h[ti][r], 0.0f));
        short8 a0 = *(const short8*)hr;
        short8 a1 = *(const short8*)(hr + 32);
        z = MFMA16(a1, BWe2[1], MFMA16(a0, BWe2[0], zero4));
    }

    // ODE func: input A-frag (16 batch x K32 of z'), output C-layout f32x4
    auto odef = [&](short8 az) -> f32x4 {
        f32x4 hh[4];
#pragma unroll
        for (int ti = 0; ti < 4; ti++) hh[ti] = MFMA16(az, BWo1[ti], zero4);
#pragma unroll
        for (int ti = 0; ti < 4; ti++)
#pragma unroll
            for (int r = 0; r < 4; r++)
                hw[r * HSTR + 16 * ti] = f2bf(fast_tanh(hh[ti][r]));
        short8 a0 = *(const short8*)hr;
        short8 a1 = *(const short8*)(hr + 32);
        return MFMA16(a1, BWo2[1], MFMA16(a0, BWo2[0], zero4));
    };

    // write z' (C-layout regs) into zbuf cols 0..15, return A-frag
    auto z_to_afrag = [&](f32x4 zz) -> short8 {
#pragma unroll
        for (int r = 0; r < 4; r++) zw[r * ZSTR] = f2bf(zz[r]);
        return *(const short8*)zr;
    };

    // ---- main time loop: decode(z_s) -> out row s; RK4 -> z_{s+1} ----
    for (int s = 0;; s++) {
        short8 az = z_to_afrag(z);

        // decoder (shares az with k1)
        {
            f32x4 hd[4];
#pragma unroll
            for (int ti = 0; ti < 4; ti++) hd[ti] = MFMA16(az, BWd1[ti], zero4);
#pragma unroll
            for (int ti = 0; ti < 4; ti++)
#pragma unroll
                for (int r = 0; r < 4; r++)
                    hw[r * HSTR + 16 * ti] = f2bf(fmaxf(hd[ti][r], 0.0f));
            short8 a0 = *(const short8*)hr;
            short8 a1 = *(const short8*)(hr + 32);
            f32x4 y = MFMA16(a1, BWd2[1], MFMA16(a0, BWd2[0], zero4));
            if (col == 0)
                *(f32x4*)(out + (size_t)s * B + wbase + quad * 4) = y;  // rows quad*4+reg
        }

        if (s == T - 1) break;
        float dt = tt[s + 1] - tt[s];

        f32x4 k = odef(az);                      // k1
        f32x4 ksum = k;
        f32x4 ztmp = z + (0.5f * dt) * k;
        k = odef(z_to_afrag(ztmp));              // k2
        ksum += 2.0f * k;
        ztmp = z + (0.5f * dt) * k;
        k = odef(z_to_afrag(ztmp));              // k3
        ksum += 2.0f * k;
        ztmp = z + dt * k;
        k = odef(z_to_afrag(ztmp));              // k4
        z = z + (dt * (1.0f / 6.0f)) * (ksum + k);
    }
}

extern "C" void kernel_launch(void* const* d_in, const int* in_sizes, int n_in,
                              void* d_out, int out_size, void* d_ws, size_t ws_size,
                              hipStream_t stream) {
    const float* x0  = (const float*)d_in[0];
    const float* t   = (const float*)d_in[1];
    const float* We1 = (const float*)d_in[2];
    const float* be1 = (const float*)d_in[3];
    const float* We2 = (const float*)d_in[4];
    const float* be2 = (const float*)d_in[5];
    const float* Wo1 = (const float*)d_in[6];
    const float* bo1 = (const float*)d_in[7];
    const float* Wo2 = (const float*)d_in[8];
    const float* bo2 = (const float*)d_in[9];
    const float* Wd1 = (const float*)d_in[10];
    const float* bd1 = (const float*)d_in[11];
    const float* Wd2 = (const float*)d_in[12];
    const float* bd2 = (const float*)d_in[13];
    float* out = (float*)d_out;

    int B = in_sizes[0] / 2;   // 65536
    int T = in_sizes[1];       // 100

    dim3 block(64);
    dim3 grid(B / MPW);        // 4096 blocks, one wave (16 batch elements) each
    hipLaunchKernelGGL(node_kernel, grid, block, 0, stream,
                       x0, t, We1, be1, We2, be2, Wo1, bo1, Wo2, bo2,
                       Wd1, bd1, Wd2, bd2, out, B, T);
}

// Round 6
// 969.295 us; speedup vs baseline: 1.0073x; 1.0073x over previous
//
#include <hip/hip_runtime.h>

#define HID 50
#define LAT 16
#define NW  4          // independent waves per block (no barriers) - 256-thread blocks
#define BLK (NW * 64)
#define MPW 16         // batch elements per wave (one MFMA M-tile)
#define ZSTR 36        // zbuf row stride (shorts), 36 % 16 == 4 -> quad enters bank index (R5-validated: conflicts -> 0)
#define HSTR 68        // hbuf row stride (shorts), 68 % 16 == 4 -> same
#define WLDS (16 * ZSTR + 16 * HSTR)   // shorts per wave

typedef __attribute__((ext_vector_type(8))) short short8;  // 8 bf16 = 4 VGPRs
typedef __attribute__((ext_vector_type(4))) float f32x4;

#define MFMA16(a, b, c) __builtin_amdgcn_mfma_f32_16x16x32_bf16(a, b, c, 0, 0, 0)

// fp32 -> bf16 round-half-up
__device__ __forceinline__ short f2bf(float f) {
    unsigned u = __builtin_bit_cast(unsigned, f);
    return (short)((u + 0x8000u) >> 16);
}

__device__ __forceinline__ float fast_tanh(float x) {
    // tanh(x) = 1 - 2/(exp(2x)+1); exact +/-1 saturation, tanh(0)=0 exact
    float e = __expf(2.0f * x);
    return 1.0f - 2.0f * __builtin_amdgcn_rcpf(e + 1.0f);
}

// B-frag for stage-1 GEMM: W[Kreal x 50] row-major, K padded 16->32.
// k==16 is the bias slot (A supplies 1.0 there); col n==50 carries satval at k==16
// so that act(h[.,50]) == 1.0 feeds the stage-2 bias row.
__device__ __forceinline__ short8 bfragK16(const float* __restrict__ W, const float* __restrict__ bias,
                                           int Kreal, int n, int quad, float satval) {
    short8 v;
#pragma unroll
    for (int j = 0; j < 8; j++) {
        int k = quad * 8 + j;
        float f = 0.0f;
        if (n < HID) {
            if (k < Kreal)      f = W[k * HID + n];
            else if (k == LAT)  f = bias[n];
        } else if (n == HID) {
            if (k == LAT)       f = satval;
        }
        v[j] = f2bf(f);
    }
    return v;
}

// B-frag for stage-2 GEMM: W[50 x 16] row-major, K padded 50->64 in 2 chunks of 32.
// k==50 is the bias row (A supplies 1.0 there via the satval column).
__device__ __forceinline__ short8 bfragK64(const float* __restrict__ W, const float* __restrict__ bias,
                                           int n, int quad, int chunk) {
    short8 v;
#pragma unroll
    for (int j = 0; j < 8; j++) {
        int k = chunk * 32 + quad * 8 + j;
        float f = 0.0f;
        if (k < HID)       f = W[k * LAT + n];
        else if (k == HID) f = bias[n];
        v[j] = f2bf(f);
    }
    return v;
}

// Decoder stage-2 B-frag: output dim 1 (col 0 only), Wd2[50], bias bd2 at k==50.
__device__ __forceinline__ short8 bfragDec2(const float* __restrict__ Wd2, float bd2s,
                                            int n, int quad, int chunk) {
    short8 v;
#pragma unroll
    for (int j = 0; j < 8; j++) {
        int k = chunk * 32 + quad * 8 + j;
        float f = 0.0f;
        if (n == 0) {
            if (k < HID)       f = Wd2[k];
            else if (k == HID) f = bd2s;
        }
        v[j] = f2bf(f);
    }
    return v;
}

__global__ void __launch_bounds__(BLK, 4)
node_kernel(const float* __restrict__ x0, const float* __restrict__ tt,
            const float* __restrict__ We1, const float* __restrict__ be1,
            const float* __restrict__ We2, const float* __restrict__ be2,
            const float* __restrict__ Wo1, const float* __restrict__ bo1,
            const float* __restrict__ Wo2, const float* __restrict__ bo2,
            const float* __restrict__ Wd1, const float* __restrict__ bd1,
            const float* __restrict__ Wd2, const float* __restrict__ bd2,
            float* __restrict__ out, int B, int T) {
    // per-wave private LDS: zbuf [16 m][ZSTR] + hbuf [16 m][HSTR] bf16
    __shared__ short lds_s[NW * WLDS];

    const int lane = threadIdx.x & 63;
    const int wid  = __builtin_amdgcn_readfirstlane((int)(threadIdx.x >> 6));
    const int quad = lane >> 4;
    const int col  = lane & 15;
    const int wbase = blockIdx.x * (NW * MPW) + wid * MPW;

    short* zbuf = lds_s + wid * WLDS;
    short* hbuf = zbuf + 16 * ZSTR;

    // init zbuf: zero all rows, then k==16 bias slot = bf16(1.0).
    // k=17..35 stay zero forever (z writes touch only k=0..15).
    {
        int* zd = (int*)zbuf;
#pragma unroll
        for (int i = 0; i < 5; i++) {
            int idx = lane + 64 * i;
            if (idx < 16 * ZSTR / 2) zd[idx] = 0;
        }
        if (lane < MPW) zbuf[lane * ZSTR + LAT] = (short)0x3F80;
    }

    // precomputed LDS pointers (loop-invariant)
    short*       zw = zbuf + (quad * 4) * ZSTR + col;   // z' writes at zw[r*ZSTR]
    const short* zr = zbuf + col * ZSTR + quad * 8;     // A-frag read
    short*       hw = hbuf + (quad * 4) * HSTR + col;   // act writes at hw[r*HSTR + 16*ti]
    const short* hr = hbuf + col * HSTR + quad * 8;     // A-frag reads: hr[0], hr[32]

    // ---- persistent B-fragments (VGPRs for the whole kernel) ----
    short8 BWo1[4], BWd1[4];
    short8 BWo2[2], BWd2[2];
#pragma unroll
    for (int ti = 0; ti < 4; ti++) {
        BWo1[ti] = bfragK16(Wo1, bo1, LAT, col + 16 * ti, quad, 20.0f); // tanh(20)==1.0
        BWd1[ti] = bfragK16(Wd1, bd1, LAT, col + 16 * ti, quad, 1.0f);  // relu(1)==1.0
    }
#pragma unroll
    for (int c = 0; c < 2; c++) {
        BWo2[c] = bfragK64(Wo2, bo2, col, quad, c);
        BWd2[c] = bfragDec2(Wd2, bd2[0], col, quad, c);
    }
    const f32x4 zero4 = {0.0f, 0.0f, 0.0f, 0.0f};

    // ---- Encoder via MFMA (one-time; We-frags are transient) ----
    f32x4 z;
    {
        if (lane < MPW) {
            float xa = x0[2 * (wbase + lane)];
            float xb = x0[2 * (wbase + lane) + 1];
            unsigned pk = (unsigned)(unsigned short)f2bf(xa) |
                          ((unsigned)(unsigned short)f2bf(xb) << 16);
            *(unsigned*)(zbuf + lane * ZSTR) = pk;  // cols 0,1; cols 2..15 zero
        }
        short8 BWe1[4], BWe2[2];
#pragma unroll
        for (int ti = 0; ti < 4; ti++) BWe1[ti] = bfragK16(We1, be1, 2, col + 16 * ti, quad, 1.0f);
#pragma unroll
        for (int c = 0; c < 2; c++)    BWe2[c]  = bfragK64(We2, be2, col, quad, c);

        short8 az = *(const short8*)zr;
        f32x4 h[4];
#pragma unroll
        for (int ti = 0; ti < 4; ti++) h[ti] = MFMA16(az, BWe1[ti], zero4);
#pragma unroll
        for (int ti = 0; ti < 4; ti++)
#pragma unroll
            for (int r = 0; r < 4; r++)
                hw[r * HSTR + 16 * ti] = f2bf(fmaxf(h[ti][r], 0.0f));
        short8 a0 = *(const short8*)hr;
        short8 a1 = *(const short8*)(hr + 32);
        z = MFMA16(a1, BWe2[1], MFMA16(a0, BWe2[0], zero4));
    }

    // ODE func: input A-frag (16 batch x K32 of z'), output C-layout f32x4
    auto odef = [&](short8 az) -> f32x4 {
        f32x4 hh[4];
#pragma unroll
        for (int ti = 0; ti < 4; ti++) hh[ti] = MFMA16(az, BWo1[ti], zero4);
#pragma unroll
        for (int ti = 0; ti < 4; ti++)
#pragma unroll
            for (int r = 0; r < 4; r++)
                hw[r * HSTR + 16 * ti] = f2bf(fast_tanh(hh[ti][r]));
        short8 a0 = *(const short8*)hr;
        short8 a1 = *(const short8*)(hr + 32);
        return MFMA16(a1, BWo2[1], MFMA16(a0, BWo2[0], zero4));
    };

    // write z' (C-layout regs) into zbuf cols 0..15, return A-frag
    auto z_to_afrag = [&](f32x4 zz) -> short8 {
#pragma unroll
        for (int r = 0; r < 4; r++) zw[r * ZSTR] = f2bf(zz[r]);
        return *(const short8*)zr;
    };

    // ---- main time loop: decode(z_s) -> out row s; RK4 -> z_{s+1} ----
    for (int s = 0;; s++) {
        short8 az = z_to_afrag(z);

        // decoder (shares az with k1; independent chain, compiler interleaves)
        {
            f32x4 hd[4];
#pragma unroll
            for (int ti = 0; ti < 4; ti++) hd[ti] = MFMA16(az, BWd1[ti], zero4);
#pragma unroll
            for (int ti = 0; ti < 4; ti++)
#pragma unroll
                for (int r = 0; r < 4; r++)
                    hw[r * HSTR + 16 * ti] = f2bf(fmaxf(hd[ti][r], 0.0f));
            short8 a0 = *(const short8*)hr;
            short8 a1 = *(const short8*)(hr + 32);
            f32x4 y = MFMA16(a1, BWd2[1], MFMA16(a0, BWd2[0], zero4));
            if (col == 0)
                *(f32x4*)(out + (size_t)s * B + wbase + quad * 4) = y;  // rows quad*4+reg
        }

        if (s == T - 1) break;
        float dt = tt[s + 1] - tt[s];

        f32x4 k = odef(az);                      // k1
        f32x4 ksum = k;
        f32x4 ztmp = z + (0.5f * dt) * k;
        k = odef(z_to_afrag(ztmp));              // k2
        ksum += 2.0f * k;
        ztmp = z + (0.5f * dt) * k;
        k = odef(z_to_afrag(ztmp));              // k3
        ksum += 2.0f * k;
        ztmp = z + dt * k;
        k = odef(z_to_afrag(ztmp));              // k4
        z = z + (dt * (1.0f / 6.0f)) * (ksum + k);
    }
}

extern "C" void kernel_launch(void* const* d_in, const int* in_sizes, int n_in,
                              void* d_out, int out_size, void* d_ws, size_t ws_size,
                              hipStream_t stream) {
    const float* x0  = (const float*)d_in[0];
    const float* t   = (const float*)d_in[1];
    const float* We1 = (const float*)d_in[2];
    const float* be1 = (const float*)d_in[3];
    const float* We2 = (const float*)d_in[4];
    const float* be2 = (const float*)d_in[5];
    const float* Wo1 = (const float*)d_in[6];
    const float* bo1 = (const float*)d_in[7];
    const float* Wo2 = (const float*)d_in[8];
    const float* bo2 = (const float*)d_in[9];
    const float* Wd1 = (const float*)d_in[10];
    const float* bd1 = (const float*)d_in[11];
    const float* Wd2 = (const float*)d_in[12];
    const float* bd2 = (const float*)d_in[13];
    float* out = (float*)d_out;

    int B = in_sizes[0] / 2;   // 65536
    int T = in_sizes[1];       // 100

    dim3 block(BLK);
    dim3 grid(B / (NW * MPW)); // 1024 blocks, 4 independent waves each
    hipLaunchKernelGGL(node_kernel, grid, block, 0, stream,
                       x0, t, We1, be1, We2, be2, Wo1, bo1, Wo2, bo2,
                       Wd1, bd1, Wd2, bd2, out, B, T);
}

// Round 7
// 611.498 us; speedup vs baseline: 1.5968x; 1.5851x over previous
//
#include <hip/hip_runtime.h>

#define HID 50
#define LAT 16
#define NW  4          // waves per block (fully independent, no LDS, no barriers)
#define BLK (NW * 64)
#define MPW 16         // batch elements per wave

typedef __attribute__((ext_vector_type(8))) short short8;   // 8 bf16 = 4 VGPRs
typedef __attribute__((ext_vector_type(4))) float f32x4;
typedef __attribute__((ext_vector_type(4))) unsigned uint4v;

#define MFMA16(a, b, c) __builtin_amdgcn_mfma_f32_16x16x32_bf16(a, b, c, 0, 0, 0)

// pack two fp32 -> dword of 2 bf16 (round-half-up): low=lo, high=hi
__device__ __forceinline__ unsigned pkbf(float lo, float hi) {
    unsigned ul = __builtin_bit_cast(unsigned, lo) + 0x8000u;
    unsigned uh = __builtin_bit_cast(unsigned, hi) + 0x8000u;
    return __builtin_amdgcn_perm(uh, ul, 0x07060302u);  // [uh.hi16 | ul.hi16]
}

__device__ __forceinline__ float fast_tanh(float x) {
    // tanh(x) = 1 - 2/(exp(2x)+1); exact saturation, tanh(0)=0 exact
    float e = __expf(2.0f * x);
    return 1.0f - 2.0f * __builtin_amdgcn_rcpf(e + 1.0f);
}

// ---- A-frag builders (weights as MFMA A-operand; one-time setup) ----
// Layer-1 (W[Kreal x 50] row-major, transposed use): tile ti rows = permuted hid
// units kappa(ti,m) = 32*(ti>>1) + 8*(m>>2) + 4*(ti&1) + (m&3).  This permutation
// makes GEMM1's CD output registers coincide with GEMM2's B-frag slots (no shuffle).
// k-slot (q,j): j<4 -> input row 4q+j (the latent/B-side layout); (q==0,j==4) -> bias;
// kappa==63 is the sat row (bias slot = satval, so act(satval)==1.0 feeds layer-2 bias).
__device__ __forceinline__ short8 afrag1(const float* __restrict__ W, const float* __restrict__ bias,
                                         int Kreal, int ti, int q, int m, float satval) {
    int kap = 32 * (ti >> 1) + 8 * (m >> 2) + 4 * (ti & 1) + (m & 3);
    float e[8];
#pragma unroll
    for (int j = 0; j < 8; j++) {
        float f = 0.0f;
        if (kap < HID) {
            if (j < 4) {
                int row = 4 * q + j;
                if (row < Kreal) f = W[row * HID + kap];
            } else if (j == 4 && q == 0) f = bias[kap];
        } else if (kap == 63) {
            if (j == 4 && q == 0) f = satval;
        }
        e[j] = f;
    }
    uint4v d;
#pragma unroll
    for (int p = 0; p < 4; p++) d[p] = pkbf(e[2 * p], e[2 * p + 1]);
    return __builtin_bit_cast(short8, d);
}

// Layer-2 (W2[50 x N2] row-major): A2[m][kap] = W2[kap][m] for kap<50, bias at kap==63.
__device__ __forceinline__ short8 afrag2(const float* __restrict__ W2, const float* __restrict__ b2,
                                         int N2, int chunk, int q, int m) {
    float e[8];
#pragma unroll
    for (int j = 0; j < 8; j++) {
        int kap = 32 * chunk + 8 * q + j;
        float f = 0.0f;
        if (m < N2) {
            if (kap < HID)      f = W2[kap * N2 + m];
            else if (kap == 63) f = b2[m];
        }
        e[j] = f;
    }
    uint4v d;
#pragma unroll
    for (int p = 0; p < 4; p++) d[p] = pkbf(e[2 * p], e[2 * p + 1]);
    return __builtin_bit_cast(short8, d);
}

__global__ void __launch_bounds__(BLK, 4)
node_kernel(const float* __restrict__ x0, const float* __restrict__ tt,
            const float* __restrict__ We1, const float* __restrict__ be1,
            const float* __restrict__ We2, const float* __restrict__ be2,
            const float* __restrict__ Wo1, const float* __restrict__ bo1,
            const float* __restrict__ Wo2, const float* __restrict__ bo2,
            const float* __restrict__ Wd1, const float* __restrict__ bd1,
            const float* __restrict__ Wd2, const float* __restrict__ bd2,
            float* __restrict__ out, int B, int T) {
    const int lane = threadIdx.x & 63;
    const int q    = lane >> 4;          // quad
    const int c    = lane & 15;          // batch col in B/CD frags; row m in A frags
    const int wid  = threadIdx.x >> 6;
    const int wbase = blockIdx.x * (NW * MPW) + wid * MPW;

    const f32x4 zero4 = {0.0f, 0.0f, 0.0f, 0.0f};
    const unsigned biasdw = (q == 0) ? 0x3F80u : 0u;   // bf16(1.0) at k-slot j=4

    // ---- Encoder (transient frags): z^T = We2^T @ relu(We1^T @ x^T) ----
    f32x4 z;
    {
        uint4v bx = {0u, 0u, 0u, 0u};
        if (q == 0) {  // x at k=0,1; bias 1.0 at k=4
            bx[0] = pkbf(x0[2 * (wbase + c)], x0[2 * (wbase + c) + 1]);
            bx[2] = 0x3F80u;
        }
        short8 Bx = __builtin_bit_cast(short8, bx);
        f32x4 h0 = MFMA16(afrag1(We1, be1, 2, 0, q, c, 1.0f), Bx, zero4);
        f32x4 h1 = MFMA16(afrag1(We1, be1, 2, 1, q, c, 1.0f), Bx, zero4);
        f32x4 h2 = MFMA16(afrag1(We1, be1, 2, 2, q, c, 1.0f), Bx, zero4);
        f32x4 h3 = MFMA16(afrag1(We1, be1, 2, 3, q, c, 1.0f), Bx, zero4);
        uint4v d0 = {pkbf(fmaxf(h0[0], 0.f), fmaxf(h0[1], 0.f)), pkbf(fmaxf(h0[2], 0.f), fmaxf(h0[3], 0.f)),
                     pkbf(fmaxf(h1[0], 0.f), fmaxf(h1[1], 0.f)), pkbf(fmaxf(h1[2], 0.f), fmaxf(h1[3], 0.f))};
        uint4v d1 = {pkbf(fmaxf(h2[0], 0.f), fmaxf(h2[1], 0.f)), pkbf(fmaxf(h2[2], 0.f), fmaxf(h2[3], 0.f)),
                     pkbf(fmaxf(h3[0], 0.f), fmaxf(h3[1], 0.f)), pkbf(fmaxf(h3[2], 0.f), fmaxf(h3[3], 0.f))};
        z = MFMA16(afrag2(We2, be2, 16, 1, q, c), __builtin_bit_cast(short8, d1),
            MFMA16(afrag2(We2, be2, 16, 0, q, c), __builtin_bit_cast(short8, d0), zero4));
    }

    // ---- persistent weight A-frags (48 VGPRs, live whole kernel) ----
    short8 A1o[4], A1d[4], A2o[2], A2d[2];
#pragma unroll
    for (int ti = 0; ti < 4; ti++) {
        A1o[ti] = afrag1(Wo1, bo1, LAT, ti, q, c, 20.0f);  // tanh(20)==1.0
        A1d[ti] = afrag1(Wd1, bd1, LAT, ti, q, c, 1.0f);   // relu(1)==1.0
    }
#pragma unroll
    for (int ch = 0; ch < 2; ch++) {
        A2o[ch] = afrag2(Wo2, bo2, LAT, ch, q, c);
        A2d[ch] = afrag2(Wd2, bd2, 1, ch, q, c);
    }

    // z (CD layout: lat 4q+r, batch c) -> GEMM1 B-frag: k(j<4)=lat 4q+j, bias at k=4
    auto mkzfrag = [&](f32x4 zz) -> short8 {
        uint4v d = {pkbf(zz[0], zz[1]), pkbf(zz[2], zz[3]), biasdw, 0u};
        return __builtin_bit_cast(short8, d);
    };

    // ODE func, all in registers: 6 MFMA + 16 tanh + packs
    auto odef = [&](short8 zf) -> f32x4 {
        f32x4 h0 = MFMA16(A1o[0], zf, zero4);
        f32x4 h1 = MFMA16(A1o[1], zf, zero4);
        f32x4 h2 = MFMA16(A1o[2], zf, zero4);
        f32x4 h3 = MFMA16(A1o[3], zf, zero4);
        uint4v d0 = {pkbf(fast_tanh(h0[0]), fast_tanh(h0[1])), pkbf(fast_tanh(h0[2]), fast_tanh(h0[3])),
                     pkbf(fast_tanh(h1[0]), fast_tanh(h1[1])), pkbf(fast_tanh(h1[2]), fast_tanh(h1[3]))};
        uint4v d1 = {pkbf(fast_tanh(h2[0]), fast_tanh(h2[1])), pkbf(fast_tanh(h2[2]), fast_tanh(h2[3])),
                     pkbf(fast_tanh(h3[0]), fast_tanh(h3[1])), pkbf(fast_tanh(h3[2]), fast_tanh(h3[3]))};
        return MFMA16(A2o[1], __builtin_bit_cast(short8, d1),
               MFMA16(A2o[0], __builtin_bit_cast(short8, d0), zero4));
    };

    // decoder: y[c] lands in reg0 of q==0 lanes
    auto decode = [&](short8 zf) -> f32x4 {
        f32x4 h0 = MFMA16(A1d[0], zf, zero4);
        f32x4 h1 = MFMA16(A1d[1], zf, zero4);
        f32x4 h2 = MFMA16(A1d[2], zf, zero4);
        f32x4 h3 = MFMA16(A1d[3], zf, zero4);
        uint4v d0 = {pkbf(fmaxf(h0[0], 0.f), fmaxf(h0[1], 0.f)), pkbf(fmaxf(h0[2], 0.f), fmaxf(h0[3], 0.f)),
                     pkbf(fmaxf(h1[0], 0.f), fmaxf(h1[1], 0.f)), pkbf(fmaxf(h1[2], 0.f), fmaxf(h1[3], 0.f))};
        uint4v d1 = {pkbf(fmaxf(h2[0], 0.f), fmaxf(h2[1], 0.f)), pkbf(fmaxf(h2[2], 0.f), fmaxf(h2[3], 0.f)),
                     pkbf(fmaxf(h3[0], 0.f), fmaxf(h3[1], 0.f)), pkbf(fmaxf(h3[2], 0.f), fmaxf(h3[3], 0.f))};
        return MFMA16(A2d[1], __builtin_bit_cast(short8, d1),
               MFMA16(A2d[0], __builtin_bit_cast(short8, d0), zero4));
    };

    // ---- main time loop: pure register dataflow, no LDS, no barriers ----
    for (int s = 0;; s++) {
        short8 zf = mkzfrag(z);
        f32x4 y = decode(zf);
        if (lane < 16) out[(size_t)s * B + wbase + c] = y[0];

        if (s == T - 1) break;
        float dt = tt[s + 1] - tt[s];

        f32x4 k = odef(zf);                          // k1 (shares zf with decode)
        f32x4 ksum = k;
        f32x4 ztmp = z + (0.5f * dt) * k;
        k = odef(mkzfrag(ztmp));                     // k2
        ksum += 2.0f * k;
        ztmp = z + (0.5f * dt) * k;
        k = odef(mkzfrag(ztmp));                     // k3
        ksum += 2.0f * k;
        ztmp = z + dt * k;
        k = odef(mkzfrag(ztmp));                     // k4
        z = z + (dt * (1.0f / 6.0f)) * (ksum + k);
    }
}

extern "C" void kernel_launch(void* const* d_in, const int* in_sizes, int n_in,
                              void* d_out, int out_size, void* d_ws, size_t ws_size,
                              hipStream_t stream) {
    const float* x0  = (const float*)d_in[0];
    const float* t   = (const float*)d_in[1];
    const float* We1 = (const float*)d_in[2];
    const float* be1 = (const float*)d_in[3];
    const float* We2 = (const float*)d_in[4];
    const float* be2 = (const float*)d_in[5];
    const float* Wo1 = (const float*)d_in[6];
    const float* bo1 = (const float*)d_in[7];
    const float* Wo2 = (const float*)d_in[8];
    const float* bo2 = (const float*)d_in[9];
    const float* Wd1 = (const float*)d_in[10];
    const float* bd1 = (const float*)d_in[11];
    const float* Wd2 = (const float*)d_in[12];
    const float* bd2 = (const float*)d_in[13];
    float* out = (float*)d_out;

    int B = in_sizes[0] / 2;   // 65536
    int T = in_sizes[1];       // 100

    dim3 block(BLK);
    dim3 grid(B / (NW * MPW)); // 1024 blocks, 4 independent waves each
    hipLaunchKernelGGL(node_kernel, grid, block, 0, stream,
                       x0, t, We1, be1, We2, be2, Wo1, bo1, Wo2, bo2,
                       Wd1, bd1, Wd2, bd2, out, B, T);
}